// Round 11
// baseline (83.977 us; speedup 1.0000x reference)
//
#include <hip/hip_runtime.h>

typedef unsigned short u16;
typedef unsigned int u32;

#define BB 8
#define CC 128
#define TT_ 1000
#define TPAD 1024
#define NB 31
#define MAXBW 16
#define MAXOC 128

typedef __bf16 bf16x8 __attribute__((ext_vector_type(8)));
typedef float f32x4 __attribute__((ext_vector_type(4)));

__device__ __forceinline__ u16 f2bf(float f) {
    u32 u = __float_as_uint(f);
    return (u16)((u + 0x7fffu + ((u >> 16) & 1u)) >> 16);
}
__device__ __forceinline__ float bf2f(u16 h) { return __uint_as_float(((u32)h) << 16); }
__device__ __forceinline__ int bandBW(int i) { return (i < 10) ? 3 : ((i < 22) ? 8 : ((i < 30) ? 16 : 3)); }
__device__ __forceinline__ int bandF0(int i) {
    return (i < 10) ? 3 * i : ((i < 22) ? 30 + 8 * (i - 10) : ((i < 30) ? 126 + 16 * (i - 22) : 254));
}

// ==================== FULL PATH ====================

// kstat v10: global_load_lds streaming transpose.
// Block = (t-window of 16, c-group of 16, b). 32 async 16B-wide direct-to-LDS
// loads stream 16 c-runs (1984B each) of f32 into LDS with ZERO VGPR staging
// (m97 primitive; dest = wave-uniform base + lane*16, m104). f32->bf16 moves
// to the store pass; stats now reduce f32 (closer to reference numerics).
// xt layout unchanged: [bl][band][cblk 16][t 1024][8c] bf16, 256B store runs.
__global__ __launch_bounds__(256, 5) void kstat(const float* __restrict__ x,
                                                u16* __restrict__ xt,
                                                float* __restrict__ partials,
                                                int b0) {
    const int tw = blockIdx.x, cg = blockIdx.y, bl = blockIdx.z, b = b0 + bl;
    const int tid = threadIdx.x, lane = tid & 63, w = tid >> 6;
    __shared__ __align__(16) float tile[16 * 500];   // 32,000 B (f32)
    const int NF4 = (tw == 62) ? 62 : 124;           // float4 per c-run

    if (tw == 62) {                                  // zero-fill (t>=1000 pad)
        for (int n = tid; n < 8000; n += 256) tile[n] = 0.f;
        __syncthreads();
    }

    const f32x4* src4 = (const f32x4*)(x + (size_t)b * (CC * TT_ * NB));
    const int fbase = tw * 124;

    // ---- async load phase: 4 c-rows per wave, 2 direct-to-LDS instrs each ----
    #pragma unroll
    for (int k = 0; k < 4; ++k) {
        const int cl = w * 4 + k;                    // 0..15
        const int c  = cg * 16 + cl;
        const f32x4* p = src4 + (size_t)c * 7750 + fbase;
        float* ldsrow = tile + cl * 500;
        if (lane < NF4)
            __builtin_amdgcn_global_load_lds(
                (const __attribute__((address_space(1))) u32*)(p + lane),
                (__attribute__((address_space(3))) u32*)ldsrow, 16, 0, 0);
        if (lane + 64 < NF4)                         // o<=123 only (row-safe)
            __builtin_amdgcn_global_load_lds(
                (const __attribute__((address_space(1))) u32*)(p + 64 + lane),
                (__attribute__((address_space(3))) u32*)(ldsrow + 256), 16, 0, 0);
    }
    __syncthreads();   // compiler drains vmcnt(0) before s_barrier (m97)

    // ---- store pass: gather 8 c's, convert f32->bf16, write 256B runs ----
    uint4* dst4 = (uint4*)xt;
    const int t0 = tw * 16;
    for (int n = tid; n < 992; n += 256) {           // 62 tasks * 16 t
        int task = n >> 4, m = n & 15;               // m = t-local
        int band = task >> 1, cbl = task & 1;
        int fidx = m * 31 + band;
        u16 e[8];
        #pragma unroll
        for (int j = 0; j < 8; ++j)
            e[j] = f2bf(tile[(8 * cbl + j) * 500 + fidx]);
        uint4 u;
        u.x = (u32)e[0] | ((u32)e[1] << 16);
        u.y = (u32)e[2] | ((u32)e[3] << 16);
        u.z = (u32)e[4] | ((u32)e[5] << 16);
        u.w = (u32)e[6] | ((u32)e[7] << 16);
        dst4[((size_t)(bl * NB + band) * 16 + (cg * 2 + cbl)) * TPAD + t0 + m] = u;
    }

    // ---- stats: 8 lanes/band over f32 tile, shfl reduce ----
    if (tid < 248) {
        int band = tid >> 3, slot = tid & 7;
        float s = 0.f, sq = 0.f;
        #pragma unroll
        for (int ci = 0; ci < 16; ++ci) {
            #pragma unroll
            for (int d = 0; d < 2; ++d) {
                float f = tile[ci * 500 + (2 * slot + d) * 31 + band];
                s += f; sq += f * f;
            }
        }
        #pragma unroll
        for (int off = 1; off < 8; off <<= 1) {
            s  += __shfl_xor(s, off);
            sq += __shfl_xor(sq, off);
        }
        if (slot == 0) {
            int ch = tw * 8 + cg;                    // 0..503
            *(float2*)&partials[((size_t)(b * NB + band) * 512 + ch) * 2] = make_float2(s, sq);
        }
    }
}

// kfoldW (standalone, once per run — r6-proven; fused variants regressed).
__global__ __launch_bounds__(128) void kfoldW(const float* __restrict__ w,
                                              const float* __restrict__ gamma,
                                              const float* __restrict__ beta,
                                              u16* __restrict__ wgT2,
                                              float* __restrict__ wbArr,
                                              float* __restrict__ wgsArr) {
    const int i = blockIdx.x, tid = threadIdx.x;
    __shared__ float g[CC], be[CC];
    g[tid] = gamma[i * CC + tid];
    be[tid] = beta[i * CC + tid];
    __syncthreads();
    const int oc = bandBW(i) * 8;
    float wb = 0.f, wgs = 0.f;
    for (int c = 0; c < CC; ++c) {
        float wv = w[(size_t)(i * MAXOC + tid) * CC + c];
        wb += wv * be[c];
        wgs += wv * g[c];
    }
    wbArr[i * CC + tid] = wb;
    wgsArr[i * CC + tid] = wgs;
    const float gc = g[tid];
    for (int o = 0; o < MAXOC; ++o) {
        float wv = w[(size_t)(i * MAXOC + o) * CC + tid];
        wgT2[(size_t)(i * MAXOC + o) * CC + tid] = (o < oc) ? f2bf(wv * gc) : (u16)0;
    }
}

// kmm v7b (r10-verified): in-register GLU epilogue via A-row permutation +
// ctx prefetch hoisted before the MFMA cluster. Only partials stride changed
// (252 chunks -> 504, array stride 512).
template <int ROWS, int WM, int WN, int RF, int CF, int TSTEP, int NSTEPS>
__device__ __forceinline__ void kmm_body(float* __restrict__ bo, float* __restrict__ red,
                                         const u16* __restrict__ xt,
                                         const u16* __restrict__ wgT2,
                                         const float* __restrict__ partials,
                                         const float* __restrict__ wbArr,
                                         const float* __restrict__ wgsArr,
                                         const float* __restrict__ cb,
                                         const float* __restrict__ ctxr,
                                         const float* __restrict__ ctxi,
                                         float* __restrict__ out,
                                         int i, int b, int bl, int bx, long long outSize) {
    const int tid = threadIdx.x;
    const int w = tid >> 6, l = tid & 63;
    const int wm = w % WM, wn = w / WM;
    const int RB = wm * 16 * RF;
    const int CB = wn * 16 * CF;
    const int lr = l & 15, lk = l >> 4;
    const int bw = bandBW(i), F0 = bandF0(i);

    // A fragments with GLU row permutation (overlaps the stats reduce)
    const uint4* wb4 = (const uint4*)(wgT2 + (size_t)i * MAXOC * CC);
    bf16x8 a[RF][4];
    #pragma unroll
    for (int rf = 0; rf < RF; ++rf) {
        const int rt = RB + rf * 16 + lr;
        const int lrow = (rt & 3) * 2 * bw + (rt >> 2);
        #pragma unroll
        for (int ks = 0; ks < 4; ++ks)
            a[rf][ks] = __builtin_bit_cast(bf16x8,
                wb4[(lrow * CC + lk * 8 + ks * 32) >> 3]);
    }

    // fused stats reduction (504 chunks, stride 512)
    float s = 0.f, sq = 0.f;
    for (int n = tid; n < 504; n += 256) {
        float2 p = *(const float2*)&partials[((size_t)(b * NB + i) * 512 + n) * 2];
        s += p.x; sq += p.y;
    }
    #pragma unroll
    for (int off = 1; off < 64; off <<= 1) {
        s  += __shfl_xor(s, off);
        sq += __shfl_xor(sq, off);
    }
    if ((tid & 63) == 0) {
        red[(tid >> 6) * 2]     = s;
        red[(tid >> 6) * 2 + 1] = sq;
    }
    __syncthreads();
    s  = red[0] + red[2] + red[4] + red[6];
    sq = red[1] + red[3] + red[5] + red[7];
    const float mean = s * (1.f / 128000.f);
    const float var  = sq * (1.f / 128000.f) - mean * mean;
    const float rstd = rsqrtf(var + 1e-8f);
    if (tid < ROWS)
        bo[tid] = cb[i * MAXOC + tid] + wbArr[i * CC + tid] - mean * rstd * wgsArr[i * CC + tid];
    __syncthreads();

    // per-rf quad info (bias quad, ctx/out row offsets, validity)
    bool  qv[RF];
    float bq[RF][4];
    size_t coff[RF];
    long long roff[RF];
    #pragma unroll
    for (int rf = 0; rf < RF; ++rf) {
        int q = RB / 4 + rf * 4 + lk;
        qv[rf] = (q < 2 * bw);
        int qc = qv[rf] ? q : 0;
        int ss = (qc >= bw) ? 1 : 0;
        int f  = qc - ss * bw;
        bq[rf][0] = bo[qc];
        bq[rf][1] = bo[2 * bw + qc];
        bq[rf][2] = bo[4 * bw + qc];
        bq[rf][3] = bo[6 * bw + qc];
        coff[rf] = ((size_t)(i * BB + b) * MAXBW + f) * TT_;
        roff[rf] = ((long long)((b * 2 + ss) * 257 + F0 + f)) * TT_;
    }

    const uint4* xb4 = ((const uint4*)xt) + (size_t)(bl * NB + i) * 16 * TPAD;

    for (int st = 0; st < NSTEPS; ++st) {
        const int t0 = (bx * NSTEPS + st) * TSTEP;

        // B fragments (blocked-c layout: cblk = lk + 4*ks)
        bf16x8 bf[CF][4];
        #pragma unroll
        for (int cf = 0; cf < CF; ++cf)
            #pragma unroll
            for (int ks = 0; ks < 4; ++ks)
                bf[cf][ks] = __builtin_bit_cast(bf16x8,
                    xb4[(size_t)(lk + ks * 4) * TPAD + (t0 + CB + cf * 16 + lr)]);

        // ctx prefetch: issue before MFMA cluster (latency hidden under MFMA)
        float crv[RF][CF], civ[RF][CF];
        #pragma unroll
        for (int rf = 0; rf < RF; ++rf)
            #pragma unroll
            for (int cf = 0; cf < CF; ++cf) {
                int t = t0 + CB + cf * 16 + lr;
                int tc = (t < TT_) ? t : 0;          // clamp: avoid tail OOB
                crv[rf][cf] = ctxr[coff[rf] + tc];
                civ[rf][cf] = ctxi[coff[rf] + tc];
            }

        f32x4 acc[RF][CF];
        #pragma unroll
        for (int rf = 0; rf < RF; ++rf)
            #pragma unroll
            for (int cf = 0; cf < CF; ++cf)
                acc[rf][cf] = (f32x4){0.f, 0.f, 0.f, 0.f};

        #pragma unroll
        for (int ks = 0; ks < 4; ++ks)
            #pragma unroll
            for (int rf = 0; rf < RF; ++rf)
                #pragma unroll
                for (int cf = 0; cf < CF; ++cf)
                    acc[rf][cf] = __builtin_amdgcn_mfma_f32_16x16x32_bf16(
                        a[rf][ks], bf[cf][ks], acc[rf][cf], 0, 0, 0);

        // in-register epilogue: bias+relu -> GLU -> complex mask -> store
        #pragma unroll
        for (int rf = 0; rf < RF; ++rf)
            #pragma unroll
            for (int cf = 0; cf < CF; ++cf) {
                const int t = t0 + CB + cf * 16 + lr;
                if (qv[rf] && t < TT_) {
                    float a0 = fmaxf(rstd * acc[rf][cf][0] + bq[rf][0], 0.f);
                    float a1 = fmaxf(rstd * acc[rf][cf][1] + bq[rf][1], 0.f);
                    float a2 = fmaxf(rstd * acc[rf][cf][2] + bq[rf][2], 0.f);
                    float a3 = fmaxf(rstd * acc[rf][cf][3] + bq[rf][3], 0.f);
                    float mr = a0 * (1.f / (1.f + __expf(-a2)));
                    float mi = a1 * (1.f / (1.f + __expf(-a3)));
                    long long ridx = roff[rf] + t;
                    if (ridx < outSize)
                        out[ridx] = crv[rf][cf] * mr - civ[rf][cf] * mi;
                }
            }
    }
}

__global__ __launch_bounds__(256) void kmm(const u16* __restrict__ xt,
                                           const u16* __restrict__ wgT2,
                                           const float* __restrict__ partials,
                                           const float* __restrict__ wbArr,
                                           const float* __restrict__ wgsArr,
                                           const float* __restrict__ cb,
                                           const float* __restrict__ ctxr,
                                           const float* __restrict__ ctxi,
                                           float* __restrict__ out,
                                           int b0, long long outSize) {
    __shared__ float bo[128];
    __shared__ float red[8];
    const int bx = blockIdx.x, i = blockIdx.y, bl = blockIdx.z, b = b0 + bl;
    if (i < 10 || i == 30)
        kmm_body<32, 2, 2, 1, 4, 128, 1>(bo, red, xt, wgT2, partials, wbArr, wgsArr, cb, ctxr, ctxi, out, i, b, bl, bx, outSize);
    else if (i < 22)
        kmm_body<64, 4, 1, 1, 4, 64, 2>(bo, red, xt, wgT2, partials, wbArr, wgsArr, cb, ctxr, ctxi, out, i, b, bl, bx, outSize);
    else
        kmm_body<128, 4, 1, 2, 2, 32, 4>(bo, red, xt, wgT2, partials, wbArr, wgsArr, cb, ctxr, ctxi, out, i, b, bl, bx, outSize);
}

// ==================== FALLBACK (zero workspace) ====================
template <int ROWS, int RPT, int BCLASS>
__global__ __launch_bounds__(256) void kreal(const float* __restrict__ x,
                                             const float* __restrict__ ctxr,
                                             const float* __restrict__ ctxi,
                                             const float* __restrict__ gamma,
                                             const float* __restrict__ beta,
                                             const float* __restrict__ w,
                                             const float* __restrict__ cb,
                                             float* __restrict__ out,
                                             long long outSize) {
    constexpr int TCH = 64, TPT = 4;
    const int by = blockIdx.x, b = blockIdx.y;
    const int i = (BCLASS == 0) ? (by < 10 ? by : 30) : (BCLASS == 1 ? 10 + by : 22 + by);
    const int tid = threadIdx.x, tx = tid & 15, ty = tid >> 4;

    __shared__ float XN[CC][TCH];
    __shared__ float WT[16][ROWS];
    __shared__ float gl[CC], bt[CC];
    __shared__ float red[8];

    const float* xb = x + (size_t)b * CC * TT_ * NB + i;

    if (tid < CC) { gl[tid] = gamma[i * CC + tid]; bt[tid] = beta[i * CC + tid]; }

    float s = 0.f, sq = 0.f;
    for (int n = tid; n < CC * TT_; n += 256) {
        float v = xb[(size_t)n * NB];
        s += v; sq += v * v;
    }
    #pragma unroll
    for (int off = 1; off < 64; off <<= 1) {
        s  += __shfl_xor(s, off);
        sq += __shfl_xor(sq, off);
    }
    if ((tid & 63) == 0) { red[(tid >> 6) * 2] = s; red[(tid >> 6) * 2 + 1] = sq; }
    __syncthreads();
    s  = red[0] + red[2] + red[4] + red[6];
    sq = red[1] + red[3] + red[5] + red[7];
    const float mean = s * (1.f / 128000.f);
    const float var  = sq * (1.f / 128000.f) - mean * mean;
    const float rstd = rsqrtf(var + 1e-8f);

    const int bw = bandBW(i), F0 = bandF0(i);
    const float* wband = w + (size_t)i * MAXOC * CC;

    for (int t0 = 0; t0 < TT_; t0 += TCH) {
        __syncthreads();
        for (int n = tid; n < CC * TCH; n += 256) {
            int c = n / TCH, tl = n % TCH;
            int t = t0 + tl;
            float v = (t < TT_) ? xb[((size_t)c * TT_ + t) * NB] : 0.f;
            XN[c][tl] = (v - mean) * rstd * gl[c] + bt[c];
        }

        float acc[RPT][TPT];
        #pragma unroll
        for (int r = 0; r < RPT; ++r)
            #pragma unroll
            for (int q = 0; q < TPT; ++q) acc[r][q] = 0.f;

        for (int k0 = 0; k0 < CC; k0 += 16) {
            for (int n = tid; n < 16 * ROWS; n += 256) {
                int kk = n / ROWS, o = n % ROWS;
                WT[kk][o] = wband[(size_t)o * CC + (k0 + kk)];
            }
            __syncthreads();
            #pragma unroll
            for (int kk = 0; kk < 16; ++kk) {
                float wv[RPT], xv[TPT];
                #pragma unroll
                for (int r = 0; r < RPT; ++r) wv[r] = WT[kk][ty * RPT + r];
                #pragma unroll
                for (int q = 0; q < TPT; ++q) xv[q] = XN[k0 + kk][tx * TPT + q];
                #pragma unroll
                for (int r = 0; r < RPT; ++r)
                    #pragma unroll
                    for (int q = 0; q < TPT; ++q) acc[r][q] = fmaf(wv[r], xv[q], acc[r][q]);
            }
            __syncthreads();
        }

        float* Yb = &XN[0][0];
        #pragma unroll
        for (int r = 0; r < RPT; ++r) {
            int o = ty * RPT + r;
            float bv = cb[i * MAXOC + o];
            #pragma unroll
            for (int q = 0; q < TPT; ++q)
                Yb[o * TCH + tx * TPT + q] = fmaxf(acc[r][q] + bv, 0.f);
        }
        __syncthreads();

        const int jobs = 2 * bw * TCH;
        for (int n = tid; n < jobs; n += 256) {
            int tl = n % TCH, sf = n / TCH;
            int ss = sf / bw, f = sf - ss * bw;
            int t = t0 + tl;
            if (t < TT_) {
                float lrv = Yb[(ss * bw + f) * TCH + tl];
                float liv = Yb[(2 * bw + ss * bw + f) * TCH + tl];
                float grv = Yb[(4 * bw + ss * bw + f) * TCH + tl];
                float giv = Yb[(6 * bw + ss * bw + f) * TCH + tl];
                float mr = lrv * (1.f / (1.f + __expf(-grv)));
                float mi = liv * (1.f / (1.f + __expf(-giv)));
                size_t cidx = ((size_t)(i * BB + b) * MAXBW + f) * TT_ + t;
                float cr = ctxr[cidx], ci = ctxi[cidx];
                long long ridx = ((long long)((b * 2 + ss) * 257 + F0 + f)) * TT_ + t;
                if (ridx < outSize) out[ridx] = cr * mr - ci * mi;
            }
        }
    }
}

extern "C" void kernel_launch(void* const* d_in, const int* in_sizes, int n_in,
                              void* d_out, int out_size, void* d_ws, size_t ws_size,
                              hipStream_t stream) {
    const float* sep   = (const float*)d_in[0];
    const float* ctxr  = (const float*)d_in[2];
    const float* ctxi  = (const float*)d_in[3];
    const float* gamma = (const float*)d_in[4];
    const float* beta  = (const float*)d_in[5];
    const float* convw = (const float*)d_in[6];
    const float* convb = (const float*)d_in[7];
    float* out = (float*)d_out;

    long long outSize = (long long)out_size;   // real plane, strictly guarded

    const size_t fixedEnd = 2063360;
    const size_t perB = (size_t)NB * 16 * TPAD * 16;  // 8,126,464 B per batch

    if (ws_size >= fixedEnd + perB) {
        char* ws = (char*)d_ws;
        float* partials = (float*)(ws + 0);          // 8*31*512*2*4 = 1,015,808 B
        float* wbArr    = (float*)(ws + 1015808);    // 15,872 B
        float* wgsArr   = (float*)(ws + 1031680);    // 15,872 B
        u16*   wgT2     = (u16*)(ws + 1047552);      // 1,015,808 B -> ends 2,063,360
        u16*   xt       = (u16*)(ws + fixedEnd);

        int nbper = (int)((ws_size - fixedEnd) / perB);
        if (nbper > BB) nbper = BB;

        kfoldW<<<dim3(NB), 128, 0, stream>>>(convw, gamma, beta, wgT2, wbArr, wgsArr);

        for (int b0 = 0; b0 < BB; b0 += nbper) {
            int nb = (BB - b0 < nbper) ? (BB - b0) : nbper;
            kstat<<<dim3(63, 8, nb), 256, 0, stream>>>(sep, xt, partials, b0);
            kmm<<<dim3(8, NB, nb), 256, 0, stream>>>(xt, wgT2, partials, wbArr, wgsArr, convb, ctxr, ctxi, out, b0, outSize);
        }
    } else {
        kreal<32, 2, 0><<<dim3(11, BB), 256, 0, stream>>>(sep, ctxr, ctxi, gamma, beta, convw, convb, out, outSize);
        kreal<64, 4, 1><<<dim3(12, BB), 256, 0, stream>>>(sep, ctxr, ctxi, gamma, beta, convw, convb, out, outSize);
        kreal<128, 8, 2><<<dim3(8, BB), 256, 0, stream>>>(sep, ctxr, ctxi, gamma, beta, convw, convb, out, outSize);
    }
}

// Round 12
// 82.991 us; speedup vs baseline: 1.0119x; 1.0119x over previous
//
#include <hip/hip_runtime.h>

typedef unsigned short u16;
typedef unsigned int u32;

#define BB 8
#define CC 128
#define TT_ 1000
#define TPAD 1024
#define NB 31
#define MAXBW 16
#define MAXOC 128

typedef __bf16 bf16x8 __attribute__((ext_vector_type(8)));
typedef float f32x4 __attribute__((ext_vector_type(4)));

__device__ __forceinline__ u16 f2bf(float f) {
    u32 u = __float_as_uint(f);
    return (u16)((u + 0x7fffu + ((u >> 16) & 1u)) >> 16);
}
__device__ __forceinline__ float bf2f(u16 h) { return __uint_as_float(((u32)h) << 16); }
__device__ __forceinline__ int bandBW(int i) { return (i < 10) ? 3 : ((i < 22) ? 8 : ((i < 30) ? 16 : 3)); }
__device__ __forceinline__ int bandF0(int i) {
    return (i < 10) ? 3 * i : ((i < 22) ? 30 + 8 * (i - 10) : ((i < 30) ? 126 + 16 * (i - 22) : 254));
}

// ==================== FULL PATH ====================

// kstat v11: r11's global_load_lds streaming transpose + foldW folded in as
// tw==63 service blocks. SAFE now (unlike r5): this kstat has no VGPR staging
// pipeline for regalloc to collapse — global_load_lds needs ~15 live VGPRs.
// tw<63: Block=(t-window 16, c-group 16, b); 32 async 16B direct-to-LDS loads;
// f32->bf16 in store pass; stats on f32 tile.
// tw==63: 8*nb blocks compute wgT2 (bf16 W*gamma) + wb/wgs dots per band.
__global__ __launch_bounds__(256, 5) void kstat(const float* __restrict__ x,
                                                const float* __restrict__ convw,
                                                const float* __restrict__ gamma,
                                                const float* __restrict__ beta,
                                                u16* __restrict__ xt,
                                                float* __restrict__ partials,
                                                u16* __restrict__ wgT2,
                                                float* __restrict__ wbArr,
                                                float* __restrict__ wgsArr,
                                                int b0) {
    const int tw = blockIdx.x, cg = blockIdx.y, bl = blockIdx.z, b = b0 + bl;
    const int tid = threadIdx.x, lane = tid & 63, w = tid >> 6;
    __shared__ __align__(16) float tile[16 * 500];   // 32,000 B (f32)

    if (tw == 63) {
        // ---- fold-W service blocks (was kfoldW; batch-independent, 31 bands) ----
        float* g  = tile;          // 128 floats
        float* be = tile + 128;
        const int nbT = (int)gridDim.z;
        for (int band = cg * nbT + bl; band < NB; band += 8 * nbT) {
            __syncthreads();
            if (tid < 128) { g[tid] = gamma[band * CC + tid]; be[tid] = beta[band * CC + tid]; }
            __syncthreads();
            const int oc = bandBW(band) * 8;
            if (tid < 128) {
                float wb = 0.f, wgs = 0.f;
                for (int c = 0; c < CC; ++c) {
                    float wv = convw[(size_t)(band * MAXOC + tid) * CC + c];
                    wb += wv * be[c];
                    wgs += wv * g[c];
                }
                wbArr[band * CC + tid] = wb;
                wgsArr[band * CC + tid] = wgs;
            }
            const int c = tid & 127, oh = tid >> 7;
            const float gc = g[c];
            for (int o = oh * 64; o < oh * 64 + 64; ++o) {
                float wv = convw[(size_t)(band * MAXOC + o) * CC + c];
                wgT2[(size_t)(band * MAXOC + o) * CC + c] = (o < oc) ? f2bf(wv * gc) : (u16)0;
            }
        }
        return;
    }

    const int NF4 = (tw == 62) ? 62 : 124;           // float4 per c-run

    if (tw == 62) {                                  // zero-fill (t>=1000 pad)
        for (int n = tid; n < 8000; n += 256) tile[n] = 0.f;
        __syncthreads();
    }

    const f32x4* src4 = (const f32x4*)(x + (size_t)b * (CC * TT_ * NB));
    const int fbase = tw * 124;

    // ---- async load phase: 4 c-rows per wave, 2 direct-to-LDS instrs each ----
    #pragma unroll
    for (int k = 0; k < 4; ++k) {
        const int cl = w * 4 + k;                    // 0..15
        const int c  = cg * 16 + cl;
        const f32x4* p = src4 + (size_t)c * 7750 + fbase;
        float* ldsrow = tile + cl * 500;
        if (lane < NF4)
            __builtin_amdgcn_global_load_lds(
                (const __attribute__((address_space(1))) u32*)(p + lane),
                (__attribute__((address_space(3))) u32*)ldsrow, 16, 0, 0);
        if (lane + 64 < NF4)                         // o<=123 only (row-safe)
            __builtin_amdgcn_global_load_lds(
                (const __attribute__((address_space(1))) u32*)(p + 64 + lane),
                (__attribute__((address_space(3))) u32*)(ldsrow + 256), 16, 0, 0);
    }
    __syncthreads();   // compiler drains vmcnt(0) before s_barrier (m97)

    // ---- store pass: gather 8 c's, convert f32->bf16, write 256B runs ----
    uint4* dst4 = (uint4*)xt;
    const int t0 = tw * 16;
    for (int n = tid; n < 992; n += 256) {           // 62 tasks * 16 t
        int task = n >> 4, m = n & 15;               // m = t-local
        int band = task >> 1, cbl = task & 1;
        int fidx = m * 31 + band;
        u16 e[8];
        #pragma unroll
        for (int j = 0; j < 8; ++j)
            e[j] = f2bf(tile[(8 * cbl + j) * 500 + fidx]);
        uint4 u;
        u.x = (u32)e[0] | ((u32)e[1] << 16);
        u.y = (u32)e[2] | ((u32)e[3] << 16);
        u.z = (u32)e[4] | ((u32)e[5] << 16);
        u.w = (u32)e[6] | ((u32)e[7] << 16);
        dst4[((size_t)(bl * NB + band) * 16 + (cg * 2 + cbl)) * TPAD + t0 + m] = u;
    }

    // ---- stats: 8 lanes/band over f32 tile, shfl reduce ----
    if (tid < 248) {
        int band = tid >> 3, slot = tid & 7;
        float s = 0.f, sq = 0.f;
        #pragma unroll
        for (int ci = 0; ci < 16; ++ci) {
            #pragma unroll
            for (int d = 0; d < 2; ++d) {
                float f = tile[ci * 500 + (2 * slot + d) * 31 + band];
                s += f; sq += f * f;
            }
        }
        #pragma unroll
        for (int off = 1; off < 8; off <<= 1) {
            s  += __shfl_xor(s, off);
            sq += __shfl_xor(sq, off);
        }
        if (slot == 0) {
            int ch = tw * 8 + cg;                    // 0..503
            *(float2*)&partials[((size_t)(b * NB + band) * 512 + ch) * 2] = make_float2(s, sq);
        }
    }
}

// kmm v7b (r10/r11-verified, unchanged): in-register GLU epilogue via A-row
// permutation + ctx prefetch before the MFMA cluster; partials stride 512.
template <int ROWS, int WM, int WN, int RF, int CF, int TSTEP, int NSTEPS>
__device__ __forceinline__ void kmm_body(float* __restrict__ bo, float* __restrict__ red,
                                         const u16* __restrict__ xt,
                                         const u16* __restrict__ wgT2,
                                         const float* __restrict__ partials,
                                         const float* __restrict__ wbArr,
                                         const float* __restrict__ wgsArr,
                                         const float* __restrict__ cb,
                                         const float* __restrict__ ctxr,
                                         const float* __restrict__ ctxi,
                                         float* __restrict__ out,
                                         int i, int b, int bl, int bx, long long outSize) {
    const int tid = threadIdx.x;
    const int w = tid >> 6, l = tid & 63;
    const int wm = w % WM, wn = w / WM;
    const int RB = wm * 16 * RF;
    const int CB = wn * 16 * CF;
    const int lr = l & 15, lk = l >> 4;
    const int bw = bandBW(i), F0 = bandF0(i);

    // A fragments with GLU row permutation (overlaps the stats reduce)
    const uint4* wb4 = (const uint4*)(wgT2 + (size_t)i * MAXOC * CC);
    bf16x8 a[RF][4];
    #pragma unroll
    for (int rf = 0; rf < RF; ++rf) {
        const int rt = RB + rf * 16 + lr;
        const int lrow = (rt & 3) * 2 * bw + (rt >> 2);
        #pragma unroll
        for (int ks = 0; ks < 4; ++ks)
            a[rf][ks] = __builtin_bit_cast(bf16x8,
                wb4[(lrow * CC + lk * 8 + ks * 32) >> 3]);
    }

    // fused stats reduction (504 chunks, stride 512)
    float s = 0.f, sq = 0.f;
    for (int n = tid; n < 504; n += 256) {
        float2 p = *(const float2*)&partials[((size_t)(b * NB + i) * 512 + n) * 2];
        s += p.x; sq += p.y;
    }
    #pragma unroll
    for (int off = 1; off < 64; off <<= 1) {
        s  += __shfl_xor(s, off);
        sq += __shfl_xor(sq, off);
    }
    if ((tid & 63) == 0) {
        red[(tid >> 6) * 2]     = s;
        red[(tid >> 6) * 2 + 1] = sq;
    }
    __syncthreads();
    s  = red[0] + red[2] + red[4] + red[6];
    sq = red[1] + red[3] + red[5] + red[7];
    const float mean = s * (1.f / 128000.f);
    const float var  = sq * (1.f / 128000.f) - mean * mean;
    const float rstd = rsqrtf(var + 1e-8f);
    if (tid < ROWS)
        bo[tid] = cb[i * MAXOC + tid] + wbArr[i * CC + tid] - mean * rstd * wgsArr[i * CC + tid];
    __syncthreads();

    // per-rf quad info (bias quad, ctx/out row offsets, validity)
    bool  qv[RF];
    float bq[RF][4];
    size_t coff[RF];
    long long roff[RF];
    #pragma unroll
    for (int rf = 0; rf < RF; ++rf) {
        int q = RB / 4 + rf * 4 + lk;
        qv[rf] = (q < 2 * bw);
        int qc = qv[rf] ? q : 0;
        int ss = (qc >= bw) ? 1 : 0;
        int f  = qc - ss * bw;
        bq[rf][0] = bo[qc];
        bq[rf][1] = bo[2 * bw + qc];
        bq[rf][2] = bo[4 * bw + qc];
        bq[rf][3] = bo[6 * bw + qc];
        coff[rf] = ((size_t)(i * BB + b) * MAXBW + f) * TT_;
        roff[rf] = ((long long)((b * 2 + ss) * 257 + F0 + f)) * TT_;
    }

    const uint4* xb4 = ((const uint4*)xt) + (size_t)(bl * NB + i) * 16 * TPAD;

    for (int st = 0; st < NSTEPS; ++st) {
        const int t0 = (bx * NSTEPS + st) * TSTEP;

        // B fragments (blocked-c layout: cblk = lk + 4*ks)
        bf16x8 bf[CF][4];
        #pragma unroll
        for (int cf = 0; cf < CF; ++cf)
            #pragma unroll
            for (int ks = 0; ks < 4; ++ks)
                bf[cf][ks] = __builtin_bit_cast(bf16x8,
                    xb4[(size_t)(lk + ks * 4) * TPAD + (t0 + CB + cf * 16 + lr)]);

        // ctx prefetch: issue before MFMA cluster (latency hidden under MFMA)
        float crv[RF][CF], civ[RF][CF];
        #pragma unroll
        for (int rf = 0; rf < RF; ++rf)
            #pragma unroll
            for (int cf = 0; cf < CF; ++cf) {
                int t = t0 + CB + cf * 16 + lr;
                int tc = (t < TT_) ? t : 0;          // clamp: avoid tail OOB
                crv[rf][cf] = ctxr[coff[rf] + tc];
                civ[rf][cf] = ctxi[coff[rf] + tc];
            }

        f32x4 acc[RF][CF];
        #pragma unroll
        for (int rf = 0; rf < RF; ++rf)
            #pragma unroll
            for (int cf = 0; cf < CF; ++cf)
                acc[rf][cf] = (f32x4){0.f, 0.f, 0.f, 0.f};

        #pragma unroll
        for (int ks = 0; ks < 4; ++ks)
            #pragma unroll
            for (int rf = 0; rf < RF; ++rf)
                #pragma unroll
                for (int cf = 0; cf < CF; ++cf)
                    acc[rf][cf] = __builtin_amdgcn_mfma_f32_16x16x32_bf16(
                        a[rf][ks], bf[cf][ks], acc[rf][cf], 0, 0, 0);

        // in-register epilogue: bias+relu -> GLU -> complex mask -> store
        #pragma unroll
        for (int rf = 0; rf < RF; ++rf)
            #pragma unroll
            for (int cf = 0; cf < CF; ++cf) {
                const int t = t0 + CB + cf * 16 + lr;
                if (qv[rf] && t < TT_) {
                    float a0 = fmaxf(rstd * acc[rf][cf][0] + bq[rf][0], 0.f);
                    float a1 = fmaxf(rstd * acc[rf][cf][1] + bq[rf][1], 0.f);
                    float a2 = fmaxf(rstd * acc[rf][cf][2] + bq[rf][2], 0.f);
                    float a3 = fmaxf(rstd * acc[rf][cf][3] + bq[rf][3], 0.f);
                    float mr = a0 * (1.f / (1.f + __expf(-a2)));
                    float mi = a1 * (1.f / (1.f + __expf(-a3)));
                    long long ridx = roff[rf] + t;
                    if (ridx < outSize)
                        out[ridx] = crv[rf][cf] * mr - civ[rf][cf] * mi;
                }
            }
    }
}

__global__ __launch_bounds__(256) void kmm(const u16* __restrict__ xt,
                                           const u16* __restrict__ wgT2,
                                           const float* __restrict__ partials,
                                           const float* __restrict__ wbArr,
                                           const float* __restrict__ wgsArr,
                                           const float* __restrict__ cb,
                                           const float* __restrict__ ctxr,
                                           const float* __restrict__ ctxi,
                                           float* __restrict__ out,
                                           int b0, long long outSize) {
    __shared__ float bo[128];
    __shared__ float red[8];
    const int bx = blockIdx.x, i = blockIdx.y, bl = blockIdx.z, b = b0 + bl;
    if (i < 10 || i == 30)
        kmm_body<32, 2, 2, 1, 4, 128, 1>(bo, red, xt, wgT2, partials, wbArr, wgsArr, cb, ctxr, ctxi, out, i, b, bl, bx, outSize);
    else if (i < 22)
        kmm_body<64, 4, 1, 1, 4, 64, 2>(bo, red, xt, wgT2, partials, wbArr, wgsArr, cb, ctxr, ctxi, out, i, b, bl, bx, outSize);
    else
        kmm_body<128, 4, 1, 2, 2, 32, 4>(bo, red, xt, wgT2, partials, wbArr, wgsArr, cb, ctxr, ctxi, out, i, b, bl, bx, outSize);
}

// ==================== FALLBACK (zero workspace) ====================
template <int ROWS, int RPT, int BCLASS>
__global__ __launch_bounds__(256) void kreal(const float* __restrict__ x,
                                             const float* __restrict__ ctxr,
                                             const float* __restrict__ ctxi,
                                             const float* __restrict__ gamma,
                                             const float* __restrict__ beta,
                                             const float* __restrict__ w,
                                             const float* __restrict__ cb,
                                             float* __restrict__ out,
                                             long long outSize) {
    constexpr int TCH = 64, TPT = 4;
    const int by = blockIdx.x, b = blockIdx.y;
    const int i = (BCLASS == 0) ? (by < 10 ? by : 30) : (BCLASS == 1 ? 10 + by : 22 + by);
    const int tid = threadIdx.x, tx = tid & 15, ty = tid >> 4;

    __shared__ float XN[CC][TCH];
    __shared__ float WT[16][ROWS];
    __shared__ float gl[CC], bt[CC];
    __shared__ float red[8];

    const float* xb = x + (size_t)b * CC * TT_ * NB + i;

    if (tid < CC) { gl[tid] = gamma[i * CC + tid]; bt[tid] = beta[i * CC + tid]; }

    float s = 0.f, sq = 0.f;
    for (int n = tid; n < CC * TT_; n += 256) {
        float v = xb[(size_t)n * NB];
        s += v; sq += v * v;
    }
    #pragma unroll
    for (int off = 1; off < 64; off <<= 1) {
        s  += __shfl_xor(s, off);
        sq += __shfl_xor(sq, off);
    }
    if ((tid & 63) == 0) { red[(tid >> 6) * 2] = s; red[(tid >> 6) * 2 + 1] = sq; }
    __syncthreads();
    s  = red[0] + red[2] + red[4] + red[6];
    sq = red[1] + red[3] + red[5] + red[7];
    const float mean = s * (1.f / 128000.f);
    const float var  = sq * (1.f / 128000.f) - mean * mean;
    const float rstd = rsqrtf(var + 1e-8f);

    const int bw = bandBW(i), F0 = bandF0(i);
    const float* wband = w + (size_t)i * MAXOC * CC;

    for (int t0 = 0; t0 < TT_; t0 += TCH) {
        __syncthreads();
        for (int n = tid; n < CC * TCH; n += 256) {
            int c = n / TCH, tl = n % TCH;
            int t = t0 + tl;
            float v = (t < TT_) ? xb[((size_t)c * TT_ + t) * NB] : 0.f;
            XN[c][tl] = (v - mean) * rstd * gl[c] + bt[c];
        }

        float acc[RPT][TPT];
        #pragma unroll
        for (int r = 0; r < RPT; ++r)
            #pragma unroll
            for (int q = 0; q < TPT; ++q) acc[r][q] = 0.f;

        for (int k0 = 0; k0 < CC; k0 += 16) {
            for (int n = tid; n < 16 * ROWS; n += 256) {
                int kk = n / ROWS, o = n % ROWS;
                WT[kk][o] = wband[(size_t)o * CC + (k0 + kk)];
            }
            __syncthreads();
            #pragma unroll
            for (int kk = 0; kk < 16; ++kk) {
                float wv[RPT], xv[TPT];
                #pragma unroll
                for (int r = 0; r < RPT; ++r) wv[r] = WT[kk][ty * RPT + r];
                #pragma unroll
                for (int q = 0; q < TPT; ++q) xv[q] = XN[k0 + kk][tx * TPT + q];
                #pragma unroll
                for (int r = 0; r < RPT; ++r)
                    #pragma unroll
                    for (int q = 0; q < TPT; ++q) acc[r][q] = fmaf(wv[r], xv[q], acc[r][q]);
            }
            __syncthreads();
        }

        float* Yb = &XN[0][0];
        #pragma unroll
        for (int r = 0; r < RPT; ++r) {
            int o = ty * RPT + r;
            float bv = cb[i * MAXOC + o];
            #pragma unroll
            for (int q = 0; q < TPT; ++q)
                Yb[o * TCH + tx * TPT + q] = fmaxf(acc[r][q] + bv, 0.f);
        }
        __syncthreads();

        const int jobs = 2 * bw * TCH;
        for (int n = tid; n < jobs; n += 256) {
            int tl = n % TCH, sf = n / TCH;
            int ss = sf / bw, f = sf - ss * bw;
            int t = t0 + tl;
            if (t < TT_) {
                float lrv = Yb[(ss * bw + f) * TCH + tl];
                float liv = Yb[(2 * bw + ss * bw + f) * TCH + tl];
                float grv = Yb[(4 * bw + ss * bw + f) * TCH + tl];
                float giv = Yb[(6 * bw + ss * bw + f) * TCH + tl];
                float mr = lrv * (1.f / (1.f + __expf(-grv)));
                float mi = liv * (1.f / (1.f + __expf(-giv)));
                size_t cidx = ((size_t)(i * BB + b) * MAXBW + f) * TT_ + t;
                float cr = ctxr[cidx], ci = ctxi[cidx];
                long long ridx = ((long long)((b * 2 + ss) * 257 + F0 + f)) * TT_ + t;
                if (ridx < outSize) out[ridx] = cr * mr - ci * mi;
            }
        }
    }
}

extern "C" void kernel_launch(void* const* d_in, const int* in_sizes, int n_in,
                              void* d_out, int out_size, void* d_ws, size_t ws_size,
                              hipStream_t stream) {
    const float* sep   = (const float*)d_in[0];
    const float* ctxr  = (const float*)d_in[2];
    const float* ctxi  = (const float*)d_in[3];
    const float* gamma = (const float*)d_in[4];
    const float* beta  = (const float*)d_in[5];
    const float* convw = (const float*)d_in[6];
    const float* convb = (const float*)d_in[7];
    float* out = (float*)d_out;

    long long outSize = (long long)out_size;   // real plane, strictly guarded

    const size_t fixedEnd = 2063360;
    const size_t perB = (size_t)NB * 16 * TPAD * 16;  // 8,126,464 B per batch

    if (ws_size >= fixedEnd + perB) {
        char* ws = (char*)d_ws;
        float* partials = (float*)(ws + 0);          // 8*31*512*2*4 = 1,015,808 B
        float* wbArr    = (float*)(ws + 1015808);    // 15,872 B
        float* wgsArr   = (float*)(ws + 1031680);    // 15,872 B
        u16*   wgT2     = (u16*)(ws + 1047552);      // 1,015,808 B -> ends 2,063,360
        u16*   xt       = (u16*)(ws + fixedEnd);

        int nbper = (int)((ws_size - fixedEnd) / perB);
        if (nbper > BB) nbper = BB;

        for (int b0 = 0; b0 < BB; b0 += nbper) {
            int nb = (BB - b0 < nbper) ? (BB - b0) : nbper;
            kstat<<<dim3(64, 8, nb), 256, 0, stream>>>(sep, convw, gamma, beta, xt, partials, wgT2, wbArr, wgsArr, b0);
            kmm<<<dim3(8, NB, nb), 256, 0, stream>>>(xt, wgT2, partials, wbArr, wgsArr, convb, ctxr, ctxi, out, b0, outSize);
        }
    } else {
        kreal<32, 2, 0><<<dim3(11, BB), 256, 0, stream>>>(sep, ctxr, ctxi, gamma, beta, convw, convb, out, outSize);
        kreal<64, 4, 1><<<dim3(12, BB), 256, 0, stream>>>(sep, ctxr, ctxi, gamma, beta, convw, convb, out, outSize);
        kreal<128, 8, 2><<<dim3(8, BB), 256, 0, stream>>>(sep, ctxr, ctxi, gamma, beta, convw, convb, out, outSize);
    }
}